// Round 16
// baseline (163.150 us; speedup 1.0000x reference)
//
#include <hip/hip_runtime.h>
#include <math.h>

#define N_NODES 100000
#define N_EDGES 1600000
#define NF 16        // node features
#define HID 32
#define OUTD 12
#define CIN3 48      // x | T_o | T_i

// Geometry: measured-best (r7/r11). p1/p3 1024-thread blocks (r11); p3 sorted
// emission (r12) + split recX/recW streams (r13); p4 sort-free u32 fixed-point
// accumulate (r15). r16: p4 gathers from a bf16 copy of x (32B lines instead
// of 64B) — tests byte-bound vs transaction-bound for the random gather.
#define NB   1024                // buckets per direction (== PT, scan assumes this)
#define RNG  98                  // nodes per bucket: 1024*98 = 100352 >= 100000
#define PBLK 256                 // partition blocks
#define PT   1024                // partition threads per block
#define CHUNK ((N_EDGES + PBLK - 1) / PBLK)   // 6250 (< 8192: fits 13 bits)

typedef unsigned int uint;
typedef unsigned short ushort;

// ============================================================================
// MAIN PATH. Two 4B record streams per direction (sorted-coalesced stores):
//   recX = other | (local << 20)       — consumed by p4 (gather)
//   recW = (local << 25) | wfix24      — consumed by kdeg (degree, u32 atomics)
// No f32 LDS atomics anywhere (slow RMW path on CDNA4, measured r6->r7).
// ============================================================================

// ---- P1: per-block bucket histograms (LDS counters); 1024 threads ----
__global__ __launch_bounds__(PT)
void p1_count(const int* __restrict__ ei, uint* __restrict__ cntD, uint* __restrict__ cntS) {
    __shared__ uint cD[NB], cS[NB];
    int t = threadIdx.x, blk = blockIdx.x;
    for (int i = t; i < NB; i += PT) { cD[i] = 0; cS[i] = 0; }
    __syncthreads();
    int lo = blk * CHUNK, hi = min(lo + CHUNK, N_EDGES);
    for (int e = lo + t; e < hi; e += PT) {
        uint s = (uint)ei[e];
        uint d = (uint)ei[N_EDGES + e];
        atomicAdd(&cS[s / RNG], 1u);
        atomicAdd(&cD[d / RNG], 1u);
    }
    __syncthreads();
    for (int i = t; i < NB; i += PT) {
        cntD[i * PBLK + blk] = cD[i];
        cntS[i * PBLK + blk] = cS[i];
    }
}

// ---- XPREP: x -> bf16 copy (RNE), [N][16] ushort ----
__global__ __launch_bounds__(256)
void xprep(const float* __restrict__ x, ushort* __restrict__ xb) {
    int i = blockIdx.x * 256 + threadIdx.x;      // one per 4 floats
    if (i >= N_NODES * NF / 4) return;
    float4 v = ((const float4*)x)[i];
    uint u0 = __float_as_uint(v.x), u1 = __float_as_uint(v.y);
    uint u2 = __float_as_uint(v.z), u3 = __float_as_uint(v.w);
    u0 += 0x7FFFu + ((u0 >> 16) & 1u); u1 += 0x7FFFu + ((u1 >> 16) & 1u);
    u2 += 0x7FFFu + ((u2 >> 16) & 1u); u3 += 0x7FFFu + ((u3 >> 16) & 1u);
    ushort4 o;
    o.x = (ushort)(u0 >> 16); o.y = (ushort)(u1 >> 16);
    o.z = (ushort)(u2 >> 16); o.w = (ushort)(u3 >> 16);
    ((ushort4*)xb)[i] = o;
}

// ---- P2a: bucket totals (row sums over blocks); grid 2*NB ----
__global__ __launch_bounds__(256)
void p2a_rowsum(const uint* __restrict__ cntD, const uint* __restrict__ cntS,
                uint* __restrict__ totD, uint* __restrict__ totS) {
    __shared__ uint red[256];
    int t = threadIdx.x;
    bool isS = blockIdx.x >= NB;
    int b = isS ? (blockIdx.x - NB) : blockIdx.x;
    const uint* cnt = isS ? cntS : cntD;
    red[t] = cnt[b * PBLK + t];
    __syncthreads();
    for (int s = 128; s > 0; s >>= 1) { if (t < s) red[t] += red[t + s]; __syncthreads(); }
    if (t == 0) (isS ? totS : totD)[b] = red[0];
}

// ---- P2b: exclusive scan of bucket totals -> baseD/baseS (NB+1 each) ----
__global__ __launch_bounds__(256)
void p2b_scan(const uint* __restrict__ totD, const uint* __restrict__ totS,
              uint* __restrict__ baseD, uint* __restrict__ baseS) {
    __shared__ uint part[256];
    int t = threadIdx.x;
    for (int dir = 0; dir < 2; ++dir) {
        const uint* tot = dir ? totS : totD;
        uint* base = dir ? baseS : baseD;
        uint v[4]; uint s = 0;
#pragma unroll
        for (int k = 0; k < 4; ++k) { v[k] = tot[t * 4 + k]; s += v[k]; }
        part[t] = s;
        __syncthreads();
        if (t == 0) {
            uint a = 0;
            for (int k = 0; k < 256; ++k) { uint x = part[k]; part[k] = a; a += x; }
            base[NB] = a;
        }
        __syncthreads();
        uint a = part[t];
#pragma unroll
        for (int k = 0; k < 4; ++k) { base[t * 4 + k] = a; a += v[k]; }
        __syncthreads();
    }
}

// ---- P2c: per-bucket exclusive scan across partition blocks + base; grid 2*NB ----
__global__ __launch_bounds__(256)
void p2c_rowscan(const uint* __restrict__ cntD, const uint* __restrict__ cntS,
                 const uint* __restrict__ baseD, const uint* __restrict__ baseS,
                 uint* __restrict__ offD, uint* __restrict__ offS) {
    __shared__ uint row[PBLK];
    int t = threadIdx.x;
    bool isS = blockIdx.x >= NB;
    int b = isS ? (blockIdx.x - NB) : blockIdx.x;
    const uint* cnt = isS ? cntS : cntD;
    const uint* base = isS ? baseS : baseD;
    uint* off = isS ? offS : offD;
    row[t] = cnt[b * PBLK + t];
    __syncthreads();
    if (t == 0) {
        uint a = base[b];
        for (int k = 0; k < PBLK; ++k) { uint v = row[k]; row[k] = a; a += v; }
    }
    __syncthreads();
    off[b * PBLK + t] = row[t];
}

// ---- P3 (r13): reuse p1 histogram, in-block sort, split coalesced emission ----
__global__ __launch_bounds__(PT)
void p3_scatter(const int* __restrict__ ei, const float* __restrict__ ew,
                const uint* __restrict__ cntD, const uint* __restrict__ cntS,
                const uint* __restrict__ offD, const uint* __restrict__ offS,
                uint* __restrict__ recXD, uint* __restrict__ recWD,
                uint* __restrict__ recXS, uint* __restrict__ recWS) {
    __shared__ uint sorted[CHUNK];        // 25000 B: (bucket<<13)|idx
    __shared__ uint sbuf[NB];             // scan buffer, then block offsets
    __shared__ uint cstart[NB];           // in-block bucket starts
    __shared__ uint scur[NB];             // placement cursors
    int t = threadIdx.x, blk = blockIdx.x;
    int lo = blk * CHUNK, hi = min(lo + CHUNK, N_EDGES);
    int n = hi - lo;

    for (int dir = 0; dir < 2; ++dir) {
        const uint* cnt = dir ? cntS : cntD;
        const uint* off = dir ? offS : offD;
        uint* recX      = dir ? recXS : recXD;
        uint* recW      = dir ? recWS : recWD;
        const int* own  = dir ? ei : (ei + N_EDGES);   // dir0: bucket by dst; dir1: by src
        uint v = cnt[t * PBLK + blk];     // PT == NB (p1's histogram, no recompute)
        sbuf[t] = v;
        __syncthreads();
        for (int d = 1; d < NB; d <<= 1) {
            uint a = (t >= d) ? sbuf[t - d] : 0u;
            __syncthreads();
            sbuf[t] += a;
            __syncthreads();
        }
        cstart[t] = sbuf[t] - v;
        scur[t]   = sbuf[t] - v;
        __syncthreads();
        sbuf[t] = off[t * PBLK + blk];    // block's global offsets
        for (int i = t; i < n; i += PT) {
            uint b = (uint)own[lo + i] / RNG;
            uint p = atomicAdd(&scur[b], 1u);
            sorted[p] = (b << 13) | (uint)i;
        }
        __syncthreads();
        for (int i = t; i < n; i += PT) {
            uint v2 = sorted[i];
            uint b = v2 >> 13;
            int e = lo + (int)(v2 & 8191u);
            uint s  = (uint)ei[e];
            uint d2 = (uint)ei[N_EDGES + e];
            uint wfix = (uint)(ew[e] * 16777216.0f + 0.5f);   // 2^24 fixed point
            uint ownode = dir ? s : d2;
            uint other  = dir ? d2 : s;
            uint lcl  = ownode - b * RNG;
            uint gpos = sbuf[b] + (i - cstart[b]);
            recX[gpos] = other | (lcl << 20);
            recW[gpos] = (lcl << 25) | wfix;
        }
        __syncthreads();
    }
}

// ---- KDEG: per-bucket weighted degree via u32 fixed-point LDS atomics ----
__global__ __launch_bounds__(256)
void kdeg(const uint* __restrict__ recWD, const uint* __restrict__ recWS,
          const uint* __restrict__ baseD, const uint* __restrict__ baseS,
          float* __restrict__ inv_in, float* __restrict__ inv_out) {
    __shared__ uint dacc[RNG];
    int t = threadIdx.x;
    bool isS = blockIdx.x >= NB;
    int b = isS ? (blockIdx.x - NB) : blockIdx.x;
    const uint* rec = isS ? recWS : recWD;
    const uint* base = isS ? baseS : baseD;
    float* inv = isS ? inv_out : inv_in;
    for (int i = t; i < RNG; i += 256) dacc[i] = 0u;
    __syncthreads();
    uint lo = base[b], hi = base[b + 1];
    for (uint e = lo + t; e < hi; e += 256) {
        uint r = rec[e];
        atomicAdd(&dacc[r >> 25], r & 0x1FFFFFFu);        // native u32 LDS atomic
    }
    __syncthreads();
    int n0 = b * RNG;
    for (int i = t; i < RNG; i += 256) {
        int n = n0 + i;
        if (n < N_NODES) inv[n] = 16777216.0f / (float)dacc[i];  // inf for isolated: never gathered
    }
}

// ---- P4 (r16): sort-free gather from BF16 x (32B lines); u32 fixed accumulate ----
__global__ __launch_bounds__(256)
void p4_fixed(const uint* __restrict__ recXD, const uint* __restrict__ recXS,
              const uint* __restrict__ baseD, const uint* __restrict__ baseS,
              const ushort* __restrict__ xb,
              const float* __restrict__ inv_out, const float* __restrict__ inv_in,
              float* __restrict__ To, float* __restrict__ Ti) {
    __shared__ uint dacc[RNG * NF];       // 6272 B -> high occupancy
    int t = threadIdx.x;
    bool isS = blockIdx.x >= NB;
    int b = isS ? (blockIdx.x - NB) : blockIdx.x;
    const uint* rec = isS ? recXS : recXD;
    const uint* base = isS ? baseS : baseD;
    const float* inv = isS ? inv_in : inv_out;
    float* out = isS ? Ti : To;
    for (int i = t; i < RNG * NF; i += 256) dacc[i] = 0u;
    __syncthreads();
    uint lo = base[b], hi = base[b + 1];
    int f = t & 15, g = t >> 4;           // 16 lanes per record (one 32B bf16 line)
    uint e = lo + g;
    // 8x unroll: 8 independent record->gather chains in flight per lane
    for (; e + 112 < hi; e += 128) {
        uint r[8];
#pragma unroll
        for (int k = 0; k < 8; ++k) r[k] = rec[e + 16 * k];
        float v[8];
#pragma unroll
        for (int k = 0; k < 8; ++k) {
            uint o = r[k] & 0xFFFFFu;
            float xv = __uint_as_float((uint)xb[(size_t)o * NF + f] << 16);
            v[k] = xv * inv[o];
        }
#pragma unroll
        for (int k = 0; k < 8; ++k)
            atomicAdd(&dacc[(r[k] >> 20) * NF + f],
                      (uint)__float2int_rn(v[k] * 1048576.0f));   // native u32 LDS atomic
    }
    for (; e < hi; e += 16) {
        uint r = rec[e];
        uint o = r & 0xFFFFFu;
        float xv = __uint_as_float((uint)xb[(size_t)o * NF + f] << 16);
        float v = xv * inv[o];
        atomicAdd(&dacc[(r >> 20) * NF + f], (uint)__float2int_rn(v * 1048576.0f));
    }
    __syncthreads();
    size_t o0 = (size_t)b * RNG * NF;
    int lim = N_NODES * NF - (int)o0;
    for (int i = t; i < RNG * NF; i += 256)
        if (i < lim) out[o0 + i] = (float)(int)dacc[i] * (1.0f / 1048576.0f);
}

// ---- combine + TRANSPOSE weights: WT[h][c] ----
__global__ void wprep_kernel(const float* __restrict__ Wz, const float* __restrict__ Wh,
                             float* __restrict__ WzT, float* __restrict__ WhT) {
    int t = blockIdx.x * blockDim.x + threadIdx.x;
    if (t >= 2 * CIN3 * HID) return;
    const float* W = (t < CIN3 * HID) ? Wz : Wh;
    float* WT      = (t < CIN3 * HID) ? WzT : WhT;
    int i = (t < CIN3 * HID) ? t : (t - CIN3 * HID);
    int c = i / HID;
    int h = i - c * HID;
    float v;
    if (c < 16)      v = W[(0 * 48 + c) * 32 + h] + W[(2 * 48 + c) * 32 + h];
    else if (c < 32) v = W[(1 * 48 + (c - 16)) * 32 + h];
    else             v = W[(3 * 48 + (c - 32)) * 32 + h];
    WT[h * CIN3 + c] = v;
}

// ---- per-node fused GRU-collapse + output ----
__global__ __launch_bounds__(256)
void node_kernel(const float* __restrict__ x, const float* __restrict__ To,
                 const float* __restrict__ Ti,
                 const float* __restrict__ WzT, const float* __restrict__ WhT,
                 const float* __restrict__ bz, const float* __restrict__ bh,
                 const float* __restrict__ linW, const float* __restrict__ linb,
                 float* __restrict__ out) {
    __shared__ __align__(16) float sWz[HID * CIN3];
    __shared__ __align__(16) float sWh[HID * CIN3];
    __shared__ __align__(16) float sBz[HID], sBh[HID];
    __shared__ __align__(16) float sLW[HID * OUTD];
    __shared__ __align__(16) float sLb[OUTD];

    for (int i = threadIdx.x; i < HID * CIN3; i += 256) { sWz[i] = WzT[i]; sWh[i] = WhT[i]; }
    if (threadIdx.x < HID) { sBz[threadIdx.x] = bz[threadIdx.x]; sBh[threadIdx.x] = bh[threadIdx.x]; }
    for (int i = threadIdx.x; i < HID * OUTD; i += 256) sLW[i] = linW[i];
    if (threadIdx.x < OUTD) sLb[threadIdx.x] = linb[threadIdx.x];
    __syncthreads();

    int n = blockIdx.x * 256 + threadIdx.x;
    if (n >= N_NODES) return;

    float feat[CIN3];
#pragma unroll
    for (int q = 0; q < 4; ++q) {
        float4 v = ((const float4*)(x + (size_t)n * NF))[q];
        feat[q*4+0]=v.x; feat[q*4+1]=v.y; feat[q*4+2]=v.z; feat[q*4+3]=v.w;
    }
#pragma unroll
    for (int q = 0; q < 4; ++q) {
        float4 v = ((const float4*)(To + (size_t)n * NF))[q];
        feat[16+q*4+0]=v.x; feat[16+q*4+1]=v.y; feat[16+q*4+2]=v.z; feat[16+q*4+3]=v.w;
    }
#pragma unroll
    for (int q = 0; q < 4; ++q) {
        float4 v = ((const float4*)(Ti + (size_t)n * NF))[q];
        feat[32+q*4+0]=v.x; feat[32+q*4+1]=v.y; feat[32+q*4+2]=v.z; feat[32+q*4+3]=v.w;
    }

    float o[OUTD];
#pragma unroll
    for (int j = 0; j < OUTD; ++j) o[j] = sLb[j];

#pragma unroll 2
    for (int h = 0; h < HID; ++h) {
        float az = sBz[h];
        float ah = sBh[h];
        const float4* wz4 = (const float4*)(sWz + h * CIN3);
        const float4* wh4 = (const float4*)(sWh + h * CIN3);
#pragma unroll
        for (int q = 0; q < CIN3 / 4; ++q) {
            float4 wz = wz4[q];
            float4 wh = wh4[q];
            float f0 = feat[q*4+0], f1 = feat[q*4+1], f2 = feat[q*4+2], f3 = feat[q*4+3];
            az += f0*wz.x + f1*wz.y + f2*wz.z + f3*wz.w;
            ah += f0*wh.x + f1*wh.y + f2*wh.z + f3*wh.w;
        }
        float z  = 1.0f / (1.0f + expf(-az));
        float ht = tanhf(ah);
        float r  = fmaxf((1.0f - z) * ht, 0.0f);
#pragma unroll
        for (int j = 0; j < OUTD; ++j) o[j] += r * sLW[h * OUTD + j];
    }

    float4* op = (float4*)(out + (size_t)n * OUTD);
    op[0] = make_float4(o[0], o[1], o[2],  o[3]);
    op[1] = make_float4(o[4], o[5], o[6],  o[7]);
    op[2] = make_float4(o[8], o[9], o[10], o[11]);
}

// ============================================================================
// FALLBACK (ws too small): compact atomic path (round-2 structure)
// ============================================================================
__global__ void zero_kernel(float* __restrict__ p, int n) {
    int i = blockIdx.x * blockDim.x + threadIdx.x;
    int stride = gridDim.x * blockDim.x;
    for (; i < n; i += stride) p[i] = 0.0f;
}
__global__ void degree_compact(const int* __restrict__ ei, const float* __restrict__ ew,
                               float* __restrict__ deg_out, float* __restrict__ deg_in) {
    int e = blockIdx.x * blockDim.x + threadIdx.x;
    if (e >= N_EDGES) return;
    atomicAdd(&deg_out[ei[e]], ew[e]);
    atomicAdd(&deg_in[ei[N_EDGES + e]], ew[e]);
}
__global__ void rcp_compact(float* __restrict__ a, float* __restrict__ b) {
    int n = blockIdx.x * blockDim.x + threadIdx.x;
    if (n >= N_NODES) return;
    a[n] = 1.0f / a[n]; b[n] = 1.0f / b[n];
}
__global__ __launch_bounds__(256)
void scatter_kernel(const int* __restrict__ ei, const float* __restrict__ x,
                    const float* __restrict__ inv_out, const float* __restrict__ inv_in,
                    float* __restrict__ To, float* __restrict__ Ti) {
    int t = blockIdx.x * blockDim.x + threadIdx.x;
    if (t >= N_EDGES * NF) return;
    int e = t >> 4, f = t & 15;
    int src = ei[e], dst = ei[N_EDGES + e];
    atomicAdd(&To[dst * NF + f], x[src * NF + f] * inv_out[src]);
    atomicAdd(&Ti[src * NF + f], x[dst * NF + f] * inv_in[dst]);
}

// ============================================================================
extern "C" void kernel_launch(void* const* d_in, const int* in_sizes, int n_in,
                              void* d_out, int out_size, void* d_ws, size_t ws_size,
                              hipStream_t stream) {
    const float* x    = (const float*)d_in[0];
    const int*   ei   = (const int*)  d_in[1];
    const float* ew   = (const float*)d_in[2];
    const float* Wz   = (const float*)d_in[3];
    const float* bz   = (const float*)d_in[4];
    // d_in[5], d_in[6] (W_r, b_r) dead: H0 == 0 makes the reset gate unused.
    const float* Wh   = (const float*)d_in[7];
    const float* bh   = (const float*)d_in[8];
    const float* linW = (const float*)d_in[9];
    const float* linb = (const float*)d_in[10];

    float* ws = (float*)d_ws;

    // ---- main-path workspace layout (dwords) ----
    size_t off = 0;
    uint* recXD = (uint*)(ws + off);  off += (size_t)N_EDGES;
    uint* recWD = (uint*)(ws + off);  off += (size_t)N_EDGES;
    uint* recXS = (uint*)(ws + off);  off += (size_t)N_EDGES;
    uint* recWS = (uint*)(ws + off);  off += (size_t)N_EDGES;
    uint* cntD  = (uint*)(ws + off);  off += (size_t)NB * PBLK;
    uint* cntS  = (uint*)(ws + off);  off += (size_t)NB * PBLK;
    uint* offD  = (uint*)(ws + off);  off += (size_t)NB * PBLK;
    uint* offS  = (uint*)(ws + off);  off += (size_t)NB * PBLK;
    uint* totD  = (uint*)(ws + off);  off += NB;
    uint* totS  = (uint*)(ws + off);  off += NB;
    uint* baseD = (uint*)(ws + off);  off += NB + 1;
    uint* baseS = (uint*)(ws + off);  off += NB + 1;
    float* inv_out = ws + off;        off += N_NODES;
    float* inv_in  = ws + off;        off += N_NODES;
    ushort* xb  = (ushort*)(ws + off); off += (size_t)N_NODES * NF / 2;
    float* To   = ws + off;           off += (size_t)NF * N_NODES;
    float* Ti   = ws + off;           off += (size_t)NF * N_NODES;
    float* WzT  = ws + off;           off += CIN3 * HID;
    float* WhT  = ws + off;           off += CIN3 * HID;
    size_t need = off * sizeof(float);

    if (ws_size >= need) {
        p1_count    <<<PBLK,  PT,  0, stream>>>(ei, cntD, cntS);
        xprep       <<<(N_NODES * NF / 4 + 255) / 256, 256, 0, stream>>>(x, xb);
        p2a_rowsum  <<<2*NB,  256, 0, stream>>>(cntD, cntS, totD, totS);
        p2b_scan    <<<1,     256, 0, stream>>>(totD, totS, baseD, baseS);
        p2c_rowscan <<<2*NB,  256, 0, stream>>>(cntD, cntS, baseD, baseS, offD, offS);
        p3_scatter  <<<PBLK,  PT,  0, stream>>>(ei, ew, cntD, cntS, offD, offS,
                                                recXD, recWD, recXS, recWS);
        kdeg        <<<2*NB,  256, 0, stream>>>(recWD, recWS, baseD, baseS, inv_in, inv_out);
        wprep_kernel<<<12,    256, 0, stream>>>(Wz, Wh, WzT, WhT);
        p4_fixed    <<<2*NB,  256, 0, stream>>>(recXD, recXS, baseD, baseS, xb,
                                                inv_out, inv_in, To, Ti);
        node_kernel <<<(N_NODES + 255) / 256, 256, 0, stream>>>(x, To, Ti, WzT, WhT, bz, bh,
                                                                linW, linb, (float*)d_out);
    } else {
        float* fTo  = ws;
        float* fTi  = ws + 16 * N_NODES;
        float* fIo  = ws + 32 * N_NODES;
        float* fIi  = ws + 33 * N_NODES;
        float* fWzT = ws + 34 * N_NODES;
        float* fWhT = fWzT + CIN3 * HID;
        zero_kernel<<<2048, 256, 0, stream>>>(fTo, 34 * N_NODES);
        degree_compact<<<(N_EDGES + 255) / 256, 256, 0, stream>>>(ei, ew, fIo, fIi);
        rcp_compact<<<(N_NODES + 255) / 256, 256, 0, stream>>>(fIo, fIi);
        scatter_kernel<<<(N_EDGES * NF + 255) / 256, 256, 0, stream>>>(ei, x, fIo, fIi, fTo, fTi);
        wprep_kernel<<<12, 256, 0, stream>>>(Wz, Wh, fWzT, fWhT);
        node_kernel<<<(N_NODES + 255) / 256, 256, 0, stream>>>(x, fTo, fTi, fWzT, fWhT, bz, bh,
                                                               linW, linb, (float*)d_out);
    }
}

// Round 17
// 157.276 us; speedup vs baseline: 1.0373x; 1.0373x over previous
//
#include <hip/hip_runtime.h>
#include <math.h>

#define N_NODES 100000
#define N_EDGES 1600000
#define NF 16        // node features
#define HID 32
#define OUTD 12
#define CIN3 48      // x | T_o | T_i

// Geometry: measured-best (r7/r11). p1/p3 1024-thread blocks (r11); p3 sorted
// emission (r12) + split recX/recW streams (r13); p4 sort-free u32 fixed-point
// accumulate (r15). r17: p4 gathers from PRE-SCALED bf16 arrays (xs=x*inv_out,
// xd=x*inv_in, 3.2MB each -> per-direction L2-resident) — ONE random load per
// record instead of two (kills the 3.2M inv dword loads).
#define NB   1024                // buckets per direction (== PT, scan assumes this)
#define RNG  98                  // nodes per bucket: 1024*98 = 100352 >= 100000
#define PBLK 256                 // partition blocks
#define PT   1024                // partition threads per block
#define CHUNK ((N_EDGES + PBLK - 1) / PBLK)   // 6250 (< 8192: fits 13 bits)

typedef unsigned int uint;
typedef unsigned short ushort;

// ============================================================================
// MAIN PATH. Two 4B record streams per direction (sorted-coalesced stores):
//   recX = other | (local << 20)       — consumed by p4 (gather)
//   recW = (local << 25) | wfix24      — consumed by kdeg (degree, u32 atomics)
// No f32 LDS atomics anywhere (slow RMW path on CDNA4, measured r6->r7).
// ============================================================================

// ---- P1: per-block bucket histograms (LDS counters); 1024 threads ----
__global__ __launch_bounds__(PT)
void p1_count(const int* __restrict__ ei, uint* __restrict__ cntD, uint* __restrict__ cntS) {
    __shared__ uint cD[NB], cS[NB];
    int t = threadIdx.x, blk = blockIdx.x;
    for (int i = t; i < NB; i += PT) { cD[i] = 0; cS[i] = 0; }
    __syncthreads();
    int lo = blk * CHUNK, hi = min(lo + CHUNK, N_EDGES);
    for (int e = lo + t; e < hi; e += PT) {
        uint s = (uint)ei[e];
        uint d = (uint)ei[N_EDGES + e];
        atomicAdd(&cS[s / RNG], 1u);
        atomicAdd(&cD[d / RNG], 1u);
    }
    __syncthreads();
    for (int i = t; i < NB; i += PT) {
        cntD[i * PBLK + blk] = cD[i];
        cntS[i * PBLK + blk] = cS[i];
    }
}

// ---- P2a: bucket totals (row sums over blocks); grid 2*NB ----
__global__ __launch_bounds__(256)
void p2a_rowsum(const uint* __restrict__ cntD, const uint* __restrict__ cntS,
                uint* __restrict__ totD, uint* __restrict__ totS) {
    __shared__ uint red[256];
    int t = threadIdx.x;
    bool isS = blockIdx.x >= NB;
    int b = isS ? (blockIdx.x - NB) : blockIdx.x;
    const uint* cnt = isS ? cntS : cntD;
    red[t] = cnt[b * PBLK + t];
    __syncthreads();
    for (int s = 128; s > 0; s >>= 1) { if (t < s) red[t] += red[t + s]; __syncthreads(); }
    if (t == 0) (isS ? totS : totD)[b] = red[0];
}

// ---- P2b: exclusive scan of bucket totals -> baseD/baseS (NB+1 each) ----
__global__ __launch_bounds__(256)
void p2b_scan(const uint* __restrict__ totD, const uint* __restrict__ totS,
              uint* __restrict__ baseD, uint* __restrict__ baseS) {
    __shared__ uint part[256];
    int t = threadIdx.x;
    for (int dir = 0; dir < 2; ++dir) {
        const uint* tot = dir ? totS : totD;
        uint* base = dir ? baseS : baseD;
        uint v[4]; uint s = 0;
#pragma unroll
        for (int k = 0; k < 4; ++k) { v[k] = tot[t * 4 + k]; s += v[k]; }
        part[t] = s;
        __syncthreads();
        if (t == 0) {
            uint a = 0;
            for (int k = 0; k < 256; ++k) { uint x = part[k]; part[k] = a; a += x; }
            base[NB] = a;
        }
        __syncthreads();
        uint a = part[t];
#pragma unroll
        for (int k = 0; k < 4; ++k) { base[t * 4 + k] = a; a += v[k]; }
        __syncthreads();
    }
}

// ---- P2c: per-bucket exclusive scan across partition blocks + base; grid 2*NB ----
__global__ __launch_bounds__(256)
void p2c_rowscan(const uint* __restrict__ cntD, const uint* __restrict__ cntS,
                 const uint* __restrict__ baseD, const uint* __restrict__ baseS,
                 uint* __restrict__ offD, uint* __restrict__ offS) {
    __shared__ uint row[PBLK];
    int t = threadIdx.x;
    bool isS = blockIdx.x >= NB;
    int b = isS ? (blockIdx.x - NB) : blockIdx.x;
    const uint* cnt = isS ? cntS : cntD;
    const uint* base = isS ? baseS : baseD;
    uint* off = isS ? offS : offD;
    row[t] = cnt[b * PBLK + t];
    __syncthreads();
    if (t == 0) {
        uint a = base[b];
        for (int k = 0; k < PBLK; ++k) { uint v = row[k]; row[k] = a; a += v; }
    }
    __syncthreads();
    off[b * PBLK + t] = row[t];
}

// ---- P3 (r13): reuse p1 histogram, in-block sort, split coalesced emission ----
__global__ __launch_bounds__(PT)
void p3_scatter(const int* __restrict__ ei, const float* __restrict__ ew,
                const uint* __restrict__ cntD, const uint* __restrict__ cntS,
                const uint* __restrict__ offD, const uint* __restrict__ offS,
                uint* __restrict__ recXD, uint* __restrict__ recWD,
                uint* __restrict__ recXS, uint* __restrict__ recWS) {
    __shared__ uint sorted[CHUNK];        // 25000 B: (bucket<<13)|idx
    __shared__ uint sbuf[NB];             // scan buffer, then block offsets
    __shared__ uint cstart[NB];           // in-block bucket starts
    __shared__ uint scur[NB];             // placement cursors
    int t = threadIdx.x, blk = blockIdx.x;
    int lo = blk * CHUNK, hi = min(lo + CHUNK, N_EDGES);
    int n = hi - lo;

    for (int dir = 0; dir < 2; ++dir) {
        const uint* cnt = dir ? cntS : cntD;
        const uint* off = dir ? offS : offD;
        uint* recX      = dir ? recXS : recXD;
        uint* recW      = dir ? recWS : recWD;
        const int* own  = dir ? ei : (ei + N_EDGES);   // dir0: bucket by dst; dir1: by src
        uint v = cnt[t * PBLK + blk];     // PT == NB (p1's histogram, no recompute)
        sbuf[t] = v;
        __syncthreads();
        for (int d = 1; d < NB; d <<= 1) {
            uint a = (t >= d) ? sbuf[t - d] : 0u;
            __syncthreads();
            sbuf[t] += a;
            __syncthreads();
        }
        cstart[t] = sbuf[t] - v;
        scur[t]   = sbuf[t] - v;
        __syncthreads();
        sbuf[t] = off[t * PBLK + blk];    // block's global offsets
        for (int i = t; i < n; i += PT) {
            uint b = (uint)own[lo + i] / RNG;
            uint p = atomicAdd(&scur[b], 1u);
            sorted[p] = (b << 13) | (uint)i;
        }
        __syncthreads();
        for (int i = t; i < n; i += PT) {
            uint v2 = sorted[i];
            uint b = v2 >> 13;
            int e = lo + (int)(v2 & 8191u);
            uint s  = (uint)ei[e];
            uint d2 = (uint)ei[N_EDGES + e];
            uint wfix = (uint)(ew[e] * 16777216.0f + 0.5f);   // 2^24 fixed point
            uint ownode = dir ? s : d2;
            uint other  = dir ? d2 : s;
            uint lcl  = ownode - b * RNG;
            uint gpos = sbuf[b] + (i - cstart[b]);
            recX[gpos] = other | (lcl << 20);
            recW[gpos] = (lcl << 25) | wfix;
        }
        __syncthreads();
    }
}

// ---- KDEG: per-bucket weighted degree via u32 fixed-point LDS atomics ----
__global__ __launch_bounds__(256)
void kdeg(const uint* __restrict__ recWD, const uint* __restrict__ recWS,
          const uint* __restrict__ baseD, const uint* __restrict__ baseS,
          float* __restrict__ inv_in, float* __restrict__ inv_out) {
    __shared__ uint dacc[RNG];
    int t = threadIdx.x;
    bool isS = blockIdx.x >= NB;
    int b = isS ? (blockIdx.x - NB) : blockIdx.x;
    const uint* rec = isS ? recWS : recWD;
    const uint* base = isS ? baseS : baseD;
    float* inv = isS ? inv_out : inv_in;
    for (int i = t; i < RNG; i += 256) dacc[i] = 0u;
    __syncthreads();
    uint lo = base[b], hi = base[b + 1];
    for (uint e = lo + t; e < hi; e += 256) {
        uint r = rec[e];
        atomicAdd(&dacc[r >> 25], r & 0x1FFFFFFu);        // native u32 LDS atomic
    }
    __syncthreads();
    int n0 = b * RNG;
    for (int i = t; i < RNG; i += 256) {
        int n = n0 + i;
        if (n < N_NODES) inv[n] = 16777216.0f / (float)dacc[i];  // inf for isolated: never gathered
    }
}

// ---- XSCALE (r17): xs = bf16(x*inv_out), xd = bf16(x*inv_in); [N][16] ----
// block of 256 handles 64 nodes; thread i -> node base+(i>>2), quad i&3.
__global__ __launch_bounds__(256)
void xscale(const float* __restrict__ x,
            const float* __restrict__ inv_out, const float* __restrict__ inv_in,
            ushort* __restrict__ xs, ushort* __restrict__ xd) {
    int i = blockIdx.x * 256 + threadIdx.x;
    int n = i >> 2, q = i & 3;
    if (n >= N_NODES) return;
    float io = inv_out[n], ii = inv_in[n];
    float4 v = ((const float4*)(x + (size_t)n * NF))[q];
    float a0 = v.x * io, a1 = v.y * io, a2 = v.z * io, a3 = v.w * io;
    float b0 = v.x * ii, b1 = v.y * ii, b2 = v.z * ii, b3 = v.w * ii;
    uint u;
    ushort4 so, sd;
    u = __float_as_uint(a0); u += 0x7FFFu + ((u >> 16) & 1u); so.x = (ushort)(u >> 16);
    u = __float_as_uint(a1); u += 0x7FFFu + ((u >> 16) & 1u); so.y = (ushort)(u >> 16);
    u = __float_as_uint(a2); u += 0x7FFFu + ((u >> 16) & 1u); so.z = (ushort)(u >> 16);
    u = __float_as_uint(a3); u += 0x7FFFu + ((u >> 16) & 1u); so.w = (ushort)(u >> 16);
    u = __float_as_uint(b0); u += 0x7FFFu + ((u >> 16) & 1u); sd.x = (ushort)(u >> 16);
    u = __float_as_uint(b1); u += 0x7FFFu + ((u >> 16) & 1u); sd.y = (ushort)(u >> 16);
    u = __float_as_uint(b2); u += 0x7FFFu + ((u >> 16) & 1u); sd.z = (ushort)(u >> 16);
    u = __float_as_uint(b3); u += 0x7FFFu + ((u >> 16) & 1u); sd.w = (ushort)(u >> 16);
    ((ushort4*)xs)[i] = so;
    ((ushort4*)xd)[i] = sd;
}

// ---- P4 (r17): single bf16-line gather per record; u32 fixed accumulate ----
// D-binned (To): gather xs[src] = x*inv_out; S-binned (Ti): xd[dst] = x*inv_in.
__global__ __launch_bounds__(256)
void p4_fixed(const uint* __restrict__ recXD, const uint* __restrict__ recXS,
              const uint* __restrict__ baseD, const uint* __restrict__ baseS,
              const ushort* __restrict__ xs, const ushort* __restrict__ xd,
              float* __restrict__ To, float* __restrict__ Ti) {
    __shared__ uint dacc[RNG * NF];       // 6272 B -> high occupancy
    int t = threadIdx.x;
    bool isS = blockIdx.x >= NB;
    int b = isS ? (blockIdx.x - NB) : blockIdx.x;
    const uint* rec = isS ? recXS : recXD;
    const uint* base = isS ? baseS : baseD;
    const ushort* src = isS ? xd : xs;
    float* out = isS ? Ti : To;
    for (int i = t; i < RNG * NF; i += 256) dacc[i] = 0u;
    __syncthreads();
    uint lo = base[b], hi = base[b + 1];
    int f = t & 15, g = t >> 4;           // 16 lanes per record (one 32B bf16 line)
    uint e = lo + g;
    // 8x unroll: 8 independent record->gather chains in flight per lane
    for (; e + 112 < hi; e += 128) {
        uint r[8];
#pragma unroll
        for (int k = 0; k < 8; ++k) r[k] = rec[e + 16 * k];
        float v[8];
#pragma unroll
        for (int k = 0; k < 8; ++k) {
            uint o = r[k] & 0xFFFFFu;
            v[k] = __uint_as_float((uint)src[(size_t)o * NF + f] << 16);
        }
#pragma unroll
        for (int k = 0; k < 8; ++k)
            atomicAdd(&dacc[(r[k] >> 20) * NF + f],
                      (uint)__float2int_rn(v[k] * 1048576.0f));   // native u32 LDS atomic
    }
    for (; e < hi; e += 16) {
        uint r = rec[e];
        uint o = r & 0xFFFFFu;
        float v = __uint_as_float((uint)src[(size_t)o * NF + f] << 16);
        atomicAdd(&dacc[(r >> 20) * NF + f], (uint)__float2int_rn(v * 1048576.0f));
    }
    __syncthreads();
    size_t o0 = (size_t)b * RNG * NF;
    int lim = N_NODES * NF - (int)o0;
    for (int i = t; i < RNG * NF; i += 256)
        if (i < lim) out[o0 + i] = (float)(int)dacc[i] * (1.0f / 1048576.0f);
}

// ---- combine + TRANSPOSE weights: WT[h][c] ----
__global__ void wprep_kernel(const float* __restrict__ Wz, const float* __restrict__ Wh,
                             float* __restrict__ WzT, float* __restrict__ WhT) {
    int t = blockIdx.x * blockDim.x + threadIdx.x;
    if (t >= 2 * CIN3 * HID) return;
    const float* W = (t < CIN3 * HID) ? Wz : Wh;
    float* WT      = (t < CIN3 * HID) ? WzT : WhT;
    int i = (t < CIN3 * HID) ? t : (t - CIN3 * HID);
    int c = i / HID;
    int h = i - c * HID;
    float v;
    if (c < 16)      v = W[(0 * 48 + c) * 32 + h] + W[(2 * 48 + c) * 32 + h];
    else if (c < 32) v = W[(1 * 48 + (c - 16)) * 32 + h];
    else             v = W[(3 * 48 + (c - 32)) * 32 + h];
    WT[h * CIN3 + c] = v;
}

// ---- per-node fused GRU-collapse + output ----
__global__ __launch_bounds__(256)
void node_kernel(const float* __restrict__ x, const float* __restrict__ To,
                 const float* __restrict__ Ti,
                 const float* __restrict__ WzT, const float* __restrict__ WhT,
                 const float* __restrict__ bz, const float* __restrict__ bh,
                 const float* __restrict__ linW, const float* __restrict__ linb,
                 float* __restrict__ out) {
    __shared__ __align__(16) float sWz[HID * CIN3];
    __shared__ __align__(16) float sWh[HID * CIN3];
    __shared__ __align__(16) float sBz[HID], sBh[HID];
    __shared__ __align__(16) float sLW[HID * OUTD];
    __shared__ __align__(16) float sLb[OUTD];

    for (int i = threadIdx.x; i < HID * CIN3; i += 256) { sWz[i] = WzT[i]; sWh[i] = WhT[i]; }
    if (threadIdx.x < HID) { sBz[threadIdx.x] = bz[threadIdx.x]; sBh[threadIdx.x] = bh[threadIdx.x]; }
    for (int i = threadIdx.x; i < HID * OUTD; i += 256) sLW[i] = linW[i];
    if (threadIdx.x < OUTD) sLb[threadIdx.x] = linb[threadIdx.x];
    __syncthreads();

    int n = blockIdx.x * 256 + threadIdx.x;
    if (n >= N_NODES) return;

    float feat[CIN3];
#pragma unroll
    for (int q = 0; q < 4; ++q) {
        float4 v = ((const float4*)(x + (size_t)n * NF))[q];
        feat[q*4+0]=v.x; feat[q*4+1]=v.y; feat[q*4+2]=v.z; feat[q*4+3]=v.w;
    }
#pragma unroll
    for (int q = 0; q < 4; ++q) {
        float4 v = ((const float4*)(To + (size_t)n * NF))[q];
        feat[16+q*4+0]=v.x; feat[16+q*4+1]=v.y; feat[16+q*4+2]=v.z; feat[16+q*4+3]=v.w;
    }
#pragma unroll
    for (int q = 0; q < 4; ++q) {
        float4 v = ((const float4*)(Ti + (size_t)n * NF))[q];
        feat[32+q*4+0]=v.x; feat[32+q*4+1]=v.y; feat[32+q*4+2]=v.z; feat[32+q*4+3]=v.w;
    }

    float o[OUTD];
#pragma unroll
    for (int j = 0; j < OUTD; ++j) o[j] = sLb[j];

#pragma unroll 2
    for (int h = 0; h < HID; ++h) {
        float az = sBz[h];
        float ah = sBh[h];
        const float4* wz4 = (const float4*)(sWz + h * CIN3);
        const float4* wh4 = (const float4*)(sWh + h * CIN3);
#pragma unroll
        for (int q = 0; q < CIN3 / 4; ++q) {
            float4 wz = wz4[q];
            float4 wh = wh4[q];
            float f0 = feat[q*4+0], f1 = feat[q*4+1], f2 = feat[q*4+2], f3 = feat[q*4+3];
            az += f0*wz.x + f1*wz.y + f2*wz.z + f3*wz.w;
            ah += f0*wh.x + f1*wh.y + f2*wh.z + f3*wh.w;
        }
        float z  = 1.0f / (1.0f + expf(-az));
        float ht = tanhf(ah);
        float r  = fmaxf((1.0f - z) * ht, 0.0f);
#pragma unroll
        for (int j = 0; j < OUTD; ++j) o[j] += r * sLW[h * OUTD + j];
    }

    float4* op = (float4*)(out + (size_t)n * OUTD);
    op[0] = make_float4(o[0], o[1], o[2],  o[3]);
    op[1] = make_float4(o[4], o[5], o[6],  o[7]);
    op[2] = make_float4(o[8], o[9], o[10], o[11]);
}

// ============================================================================
// FALLBACK (ws too small): compact atomic path (round-2 structure)
// ============================================================================
__global__ void zero_kernel(float* __restrict__ p, int n) {
    int i = blockIdx.x * blockDim.x + threadIdx.x;
    int stride = gridDim.x * blockDim.x;
    for (; i < n; i += stride) p[i] = 0.0f;
}
__global__ void degree_compact(const int* __restrict__ ei, const float* __restrict__ ew,
                               float* __restrict__ deg_out, float* __restrict__ deg_in) {
    int e = blockIdx.x * blockDim.x + threadIdx.x;
    if (e >= N_EDGES) return;
    atomicAdd(&deg_out[ei[e]], ew[e]);
    atomicAdd(&deg_in[ei[N_EDGES + e]], ew[e]);
}
__global__ void rcp_compact(float* __restrict__ a, float* __restrict__ b) {
    int n = blockIdx.x * blockDim.x + threadIdx.x;
    if (n >= N_NODES) return;
    a[n] = 1.0f / a[n]; b[n] = 1.0f / b[n];
}
__global__ __launch_bounds__(256)
void scatter_kernel(const int* __restrict__ ei, const float* __restrict__ x,
                    const float* __restrict__ inv_out, const float* __restrict__ inv_in,
                    float* __restrict__ To, float* __restrict__ Ti) {
    int t = blockIdx.x * blockDim.x + threadIdx.x;
    if (t >= N_EDGES * NF) return;
    int e = t >> 4, f = t & 15;
    int src = ei[e], dst = ei[N_EDGES + e];
    atomicAdd(&To[dst * NF + f], x[src * NF + f] * inv_out[src]);
    atomicAdd(&Ti[src * NF + f], x[dst * NF + f] * inv_in[dst]);
}

// ============================================================================
extern "C" void kernel_launch(void* const* d_in, const int* in_sizes, int n_in,
                              void* d_out, int out_size, void* d_ws, size_t ws_size,
                              hipStream_t stream) {
    const float* x    = (const float*)d_in[0];
    const int*   ei   = (const int*)  d_in[1];
    const float* ew   = (const float*)d_in[2];
    const float* Wz   = (const float*)d_in[3];
    const float* bz   = (const float*)d_in[4];
    // d_in[5], d_in[6] (W_r, b_r) dead: H0 == 0 makes the reset gate unused.
    const float* Wh   = (const float*)d_in[7];
    const float* bh   = (const float*)d_in[8];
    const float* linW = (const float*)d_in[9];
    const float* linb = (const float*)d_in[10];

    float* ws = (float*)d_ws;

    // ---- main-path workspace layout (dwords) ----
    size_t off = 0;
    uint* recXD = (uint*)(ws + off);  off += (size_t)N_EDGES;
    uint* recWD = (uint*)(ws + off);  off += (size_t)N_EDGES;
    uint* recXS = (uint*)(ws + off);  off += (size_t)N_EDGES;
    uint* recWS = (uint*)(ws + off);  off += (size_t)N_EDGES;
    uint* cntD  = (uint*)(ws + off);  off += (size_t)NB * PBLK;
    uint* cntS  = (uint*)(ws + off);  off += (size_t)NB * PBLK;
    uint* offD  = (uint*)(ws + off);  off += (size_t)NB * PBLK;
    uint* offS  = (uint*)(ws + off);  off += (size_t)NB * PBLK;
    uint* totD  = (uint*)(ws + off);  off += NB;
    uint* totS  = (uint*)(ws + off);  off += NB;
    uint* baseD = (uint*)(ws + off);  off += NB + 1;
    uint* baseS = (uint*)(ws + off);  off += NB + 1;
    float* inv_out = ws + off;        off += N_NODES;
    float* inv_in  = ws + off;        off += N_NODES;
    ushort* xs  = (ushort*)(ws + off); off += (size_t)N_NODES * NF / 2;
    ushort* xd  = (ushort*)(ws + off); off += (size_t)N_NODES * NF / 2;
    float* To   = ws + off;           off += (size_t)NF * N_NODES;
    float* Ti   = ws + off;           off += (size_t)NF * N_NODES;
    float* WzT  = ws + off;           off += CIN3 * HID;
    float* WhT  = ws + off;           off += CIN3 * HID;
    size_t need = off * sizeof(float);

    if (ws_size >= need) {
        p1_count    <<<PBLK,  PT,  0, stream>>>(ei, cntD, cntS);
        p2a_rowsum  <<<2*NB,  256, 0, stream>>>(cntD, cntS, totD, totS);
        p2b_scan    <<<1,     256, 0, stream>>>(totD, totS, baseD, baseS);
        p2c_rowscan <<<2*NB,  256, 0, stream>>>(cntD, cntS, baseD, baseS, offD, offS);
        p3_scatter  <<<PBLK,  PT,  0, stream>>>(ei, ew, cntD, cntS, offD, offS,
                                                recXD, recWD, recXS, recWS);
        kdeg        <<<2*NB,  256, 0, stream>>>(recWD, recWS, baseD, baseS, inv_in, inv_out);
        xscale      <<<(N_NODES * 4 + 255) / 256, 256, 0, stream>>>(x, inv_out, inv_in, xs, xd);
        wprep_kernel<<<12,    256, 0, stream>>>(Wz, Wh, WzT, WhT);
        p4_fixed    <<<2*NB,  256, 0, stream>>>(recXD, recXS, baseD, baseS, xs, xd, To, Ti);
        node_kernel <<<(N_NODES + 255) / 256, 256, 0, stream>>>(x, To, Ti, WzT, WhT, bz, bh,
                                                                linW, linb, (float*)d_out);
    } else {
        float* fTo  = ws;
        float* fTi  = ws + 16 * N_NODES;
        float* fIo  = ws + 32 * N_NODES;
        float* fIi  = ws + 33 * N_NODES;
        float* fWzT = ws + 34 * N_NODES;
        float* fWhT = fWzT + CIN3 * HID;
        zero_kernel<<<2048, 256, 0, stream>>>(fTo, 34 * N_NODES);
        degree_compact<<<(N_EDGES + 255) / 256, 256, 0, stream>>>(ei, ew, fIo, fIi);
        rcp_compact<<<(N_NODES + 255) / 256, 256, 0, stream>>>(fIo, fIi);
        scatter_kernel<<<(N_EDGES * NF + 255) / 256, 256, 0, stream>>>(ei, x, fIo, fIi, fTo, fTi);
        wprep_kernel<<<12, 256, 0, stream>>>(Wz, Wh, fWzT, fWhT);
        node_kernel<<<(N_NODES + 255) / 256, 256, 0, stream>>>(x, fTo, fTi, fWzT, fWhT, bz, bh,
                                                               linW, linb, (float*)d_out);
    }
}

// Round 18
// 156.426 us; speedup vs baseline: 1.0430x; 1.0054x over previous
//
#include <hip/hip_runtime.h>
#include <math.h>

#define N_NODES 100000
#define N_EDGES 1600000
#define NF 16        // node features
#define HID 32
#define OUTD 12
#define CIN3 48      // x | T_o | T_i

// Geometry: measured-best (r7/r11). p1/p3 1024-thread blocks (r11); p3 sorted
// emission (r12) + split recX/recW streams (r13); p4 sort-free u32 fixed-point
// accumulate (r15) over pre-scaled bf16 arrays (r17). r18: kdeg+xscale fused
// (inv stays in LDS, xs/xd emitted directly); wprep folded into node_kernel.
#define NB   1024                // buckets per direction (== PT, scan assumes this)
#define RNG  98                  // nodes per bucket: 1024*98 = 100352 >= 100000
#define PBLK 256                 // partition blocks
#define PT   1024                // partition threads per block
#define CHUNK ((N_EDGES + PBLK - 1) / PBLK)   // 6250 (< 8192: fits 13 bits)

typedef unsigned int uint;
typedef unsigned short ushort;

// ============================================================================
// MAIN PATH. Two 4B record streams per direction (sorted-coalesced stores):
//   recX = other | (local << 20)       — consumed by p4 (gather)
//   recW = (local << 25) | wfix24      — consumed by kdeg2 (degree, u32 atomics)
// No f32 LDS atomics anywhere (slow RMW path on CDNA4, measured r6->r7).
// ============================================================================

// ---- P1: per-block bucket histograms (LDS counters); 1024 threads ----
__global__ __launch_bounds__(PT)
void p1_count(const int* __restrict__ ei, uint* __restrict__ cntD, uint* __restrict__ cntS) {
    __shared__ uint cD[NB], cS[NB];
    int t = threadIdx.x, blk = blockIdx.x;
    for (int i = t; i < NB; i += PT) { cD[i] = 0; cS[i] = 0; }
    __syncthreads();
    int lo = blk * CHUNK, hi = min(lo + CHUNK, N_EDGES);
    for (int e = lo + t; e < hi; e += PT) {
        uint s = (uint)ei[e];
        uint d = (uint)ei[N_EDGES + e];
        atomicAdd(&cS[s / RNG], 1u);
        atomicAdd(&cD[d / RNG], 1u);
    }
    __syncthreads();
    for (int i = t; i < NB; i += PT) {
        cntD[i * PBLK + blk] = cD[i];
        cntS[i * PBLK + blk] = cS[i];
    }
}

// ---- P2a: bucket totals (row sums over blocks); grid 2*NB ----
__global__ __launch_bounds__(256)
void p2a_rowsum(const uint* __restrict__ cntD, const uint* __restrict__ cntS,
                uint* __restrict__ totD, uint* __restrict__ totS) {
    __shared__ uint red[256];
    int t = threadIdx.x;
    bool isS = blockIdx.x >= NB;
    int b = isS ? (blockIdx.x - NB) : blockIdx.x;
    const uint* cnt = isS ? cntS : cntD;
    red[t] = cnt[b * PBLK + t];
    __syncthreads();
    for (int s = 128; s > 0; s >>= 1) { if (t < s) red[t] += red[t + s]; __syncthreads(); }
    if (t == 0) (isS ? totS : totD)[b] = red[0];
}

// ---- P2b: exclusive scan of bucket totals -> baseD/baseS (NB+1 each) ----
__global__ __launch_bounds__(256)
void p2b_scan(const uint* __restrict__ totD, const uint* __restrict__ totS,
              uint* __restrict__ baseD, uint* __restrict__ baseS) {
    __shared__ uint part[256];
    int t = threadIdx.x;
    for (int dir = 0; dir < 2; ++dir) {
        const uint* tot = dir ? totS : totD;
        uint* base = dir ? baseS : baseD;
        uint v[4]; uint s = 0;
#pragma unroll
        for (int k = 0; k < 4; ++k) { v[k] = tot[t * 4 + k]; s += v[k]; }
        part[t] = s;
        __syncthreads();
        if (t == 0) {
            uint a = 0;
            for (int k = 0; k < 256; ++k) { uint x = part[k]; part[k] = a; a += x; }
            base[NB] = a;
        }
        __syncthreads();
        uint a = part[t];
#pragma unroll
        for (int k = 0; k < 4; ++k) { base[t * 4 + k] = a; a += v[k]; }
        __syncthreads();
    }
}

// ---- P2c: per-bucket exclusive scan across partition blocks + base; grid 2*NB ----
__global__ __launch_bounds__(256)
void p2c_rowscan(const uint* __restrict__ cntD, const uint* __restrict__ cntS,
                 const uint* __restrict__ baseD, const uint* __restrict__ baseS,
                 uint* __restrict__ offD, uint* __restrict__ offS) {
    __shared__ uint row[PBLK];
    int t = threadIdx.x;
    bool isS = blockIdx.x >= NB;
    int b = isS ? (blockIdx.x - NB) : blockIdx.x;
    const uint* cnt = isS ? cntS : cntD;
    const uint* base = isS ? baseS : baseD;
    uint* off = isS ? offS : offD;
    row[t] = cnt[b * PBLK + t];
    __syncthreads();
    if (t == 0) {
        uint a = base[b];
        for (int k = 0; k < PBLK; ++k) { uint v = row[k]; row[k] = a; a += v; }
    }
    __syncthreads();
    off[b * PBLK + t] = row[t];
}

// ---- P3 (r13): reuse p1 histogram, in-block sort, split coalesced emission ----
__global__ __launch_bounds__(PT)
void p3_scatter(const int* __restrict__ ei, const float* __restrict__ ew,
                const uint* __restrict__ cntD, const uint* __restrict__ cntS,
                const uint* __restrict__ offD, const uint* __restrict__ offS,
                uint* __restrict__ recXD, uint* __restrict__ recWD,
                uint* __restrict__ recXS, uint* __restrict__ recWS) {
    __shared__ uint sorted[CHUNK];        // 25000 B: (bucket<<13)|idx
    __shared__ uint sbuf[NB];             // scan buffer, then block offsets
    __shared__ uint cstart[NB];           // in-block bucket starts
    __shared__ uint scur[NB];             // placement cursors
    int t = threadIdx.x, blk = blockIdx.x;
    int lo = blk * CHUNK, hi = min(lo + CHUNK, N_EDGES);
    int n = hi - lo;

    for (int dir = 0; dir < 2; ++dir) {
        const uint* cnt = dir ? cntS : cntD;
        const uint* off = dir ? offS : offD;
        uint* recX      = dir ? recXS : recXD;
        uint* recW      = dir ? recWS : recWD;
        const int* own  = dir ? ei : (ei + N_EDGES);   // dir0: bucket by dst; dir1: by src
        uint v = cnt[t * PBLK + blk];     // PT == NB (p1's histogram, no recompute)
        sbuf[t] = v;
        __syncthreads();
        for (int d = 1; d < NB; d <<= 1) {
            uint a = (t >= d) ? sbuf[t - d] : 0u;
            __syncthreads();
            sbuf[t] += a;
            __syncthreads();
        }
        cstart[t] = sbuf[t] - v;
        scur[t]   = sbuf[t] - v;
        __syncthreads();
        sbuf[t] = off[t * PBLK + blk];    // block's global offsets
        for (int i = t; i < n; i += PT) {
            uint b = (uint)own[lo + i] / RNG;
            uint p = atomicAdd(&scur[b], 1u);
            sorted[p] = (b << 13) | (uint)i;
        }
        __syncthreads();
        for (int i = t; i < n; i += PT) {
            uint v2 = sorted[i];
            uint b = v2 >> 13;
            int e = lo + (int)(v2 & 8191u);
            uint s  = (uint)ei[e];
            uint d2 = (uint)ei[N_EDGES + e];
            uint wfix = (uint)(ew[e] * 16777216.0f + 0.5f);   // 2^24 fixed point
            uint ownode = dir ? s : d2;
            uint other  = dir ? d2 : s;
            uint lcl  = ownode - b * RNG;
            uint gpos = sbuf[b] + (i - cstart[b]);
            recX[gpos] = other | (lcl << 20);
            recW[gpos] = (lcl << 25) | wfix;
        }
        __syncthreads();
    }
}

// ---- KDEG2 (r18): both directions' degrees for this node range in LDS, then
// emit pre-scaled bf16 xs = bf16(x*inv_out), xd = bf16(x*inv_in) directly.
// Fuses old kdeg + xscale; inv arrays never touch global memory.
__global__ __launch_bounds__(256)
void kdeg2(const uint* __restrict__ recWD, const uint* __restrict__ recWS,
           const uint* __restrict__ baseD, const uint* __restrict__ baseS,
           const float* __restrict__ x,
           ushort* __restrict__ xs, ushort* __restrict__ xd) {
    __shared__ uint daccI[RNG], daccO[RNG];       // deg_in (D-binned), deg_out (S-binned)
    __shared__ float invI[RNG], invO[RNG];
    int t = threadIdx.x, b = blockIdx.x;
    for (int i = t; i < RNG; i += 256) { daccI[i] = 0u; daccO[i] = 0u; }
    __syncthreads();
    uint lo = baseD[b], hi = baseD[b + 1];
    for (uint e = lo + t; e < hi; e += 256) {
        uint r = recWD[e];
        atomicAdd(&daccI[r >> 25], r & 0x1FFFFFFu);   // native u32 LDS atomic
    }
    lo = baseS[b]; hi = baseS[b + 1];
    for (uint e = lo + t; e < hi; e += 256) {
        uint r = recWS[e];
        atomicAdd(&daccO[r >> 25], r & 0x1FFFFFFu);
    }
    __syncthreads();
    for (int i = t; i < RNG; i += 256) {
        invI[i] = 16777216.0f / (float)daccI[i];      // inf for isolated: never gathered
        invO[i] = 16777216.0f / (float)daccO[i];
    }
    __syncthreads();
    int base = b * RNG * NF;
    int lim = N_NODES * NF - base;
    for (int i = t; i < RNG * NF; i += 256) {
        if (i < lim) {
            int nl = i >> 4;
            float v = x[base + i];
            float a = v * invO[nl];
            float c = v * invI[nl];
            uint u;
            u = __float_as_uint(a); u += 0x7FFFu + ((u >> 16) & 1u);
            xs[base + i] = (ushort)(u >> 16);
            u = __float_as_uint(c); u += 0x7FFFu + ((u >> 16) & 1u);
            xd[base + i] = (ushort)(u >> 16);
        }
    }
}

// ---- P4 (r17): single bf16-line gather per record; u32 fixed accumulate ----
// D-binned (To): gather xs[src] = x*inv_out; S-binned (Ti): xd[dst] = x*inv_in.
__global__ __launch_bounds__(256)
void p4_fixed(const uint* __restrict__ recXD, const uint* __restrict__ recXS,
              const uint* __restrict__ baseD, const uint* __restrict__ baseS,
              const ushort* __restrict__ xs, const ushort* __restrict__ xd,
              float* __restrict__ To, float* __restrict__ Ti) {
    __shared__ uint dacc[RNG * NF];       // 6272 B -> high occupancy
    int t = threadIdx.x;
    bool isS = blockIdx.x >= NB;
    int b = isS ? (blockIdx.x - NB) : blockIdx.x;
    const uint* rec = isS ? recXS : recXD;
    const uint* base = isS ? baseS : baseD;
    const ushort* src = isS ? xd : xs;
    float* out = isS ? Ti : To;
    for (int i = t; i < RNG * NF; i += 256) dacc[i] = 0u;
    __syncthreads();
    uint lo = base[b], hi = base[b + 1];
    int f = t & 15, g = t >> 4;           // 16 lanes per record (one 32B bf16 line)
    uint e = lo + g;
    // 8x unroll: 8 independent record->gather chains in flight per lane
    for (; e + 112 < hi; e += 128) {
        uint r[8];
#pragma unroll
        for (int k = 0; k < 8; ++k) r[k] = rec[e + 16 * k];
        float v[8];
#pragma unroll
        for (int k = 0; k < 8; ++k) {
            uint o = r[k] & 0xFFFFFu;
            v[k] = __uint_as_float((uint)src[(size_t)o * NF + f] << 16);
        }
#pragma unroll
        for (int k = 0; k < 8; ++k)
            atomicAdd(&dacc[(r[k] >> 20) * NF + f],
                      (uint)__float2int_rn(v[k] * 1048576.0f));   // native u32 LDS atomic
    }
    for (; e < hi; e += 16) {
        uint r = rec[e];
        uint o = r & 0xFFFFFu;
        float v = __uint_as_float((uint)src[(size_t)o * NF + f] << 16);
        atomicAdd(&dacc[(r >> 20) * NF + f], (uint)__float2int_rn(v * 1048576.0f));
    }
    __syncthreads();
    size_t o0 = (size_t)b * RNG * NF;
    int lim = N_NODES * NF - (int)o0;
    for (int i = t; i < RNG * NF; i += 256)
        if (i < lim) out[o0 + i] = (float)(int)dacc[i] * (1.0f / 1048576.0f);
}

// ---- per-node fused GRU-collapse + output; weight-combine inlined (r18) ----
// sWz/sWh [h][c]: c<16 -> W[0,0,c,:]+W[1,0,c,:]; c<32 -> W[0,1,c-16,:];
// else W[1,1,c-32,:].  W layout [2,2,48,32]: (d,k,c,h) -> ((d*2+k)*48+c)*32+h.
__global__ __launch_bounds__(256)
void node_kernel(const float* __restrict__ x, const float* __restrict__ To,
                 const float* __restrict__ Ti,
                 const float* __restrict__ Wz, const float* __restrict__ Wh,
                 const float* __restrict__ bz, const float* __restrict__ bh,
                 const float* __restrict__ linW, const float* __restrict__ linb,
                 float* __restrict__ out) {
    __shared__ __align__(16) float sWz[HID * CIN3];
    __shared__ __align__(16) float sWh[HID * CIN3];
    __shared__ __align__(16) float sBz[HID], sBh[HID];
    __shared__ __align__(16) float sLW[HID * OUTD];
    __shared__ __align__(16) float sLb[OUTD];

    for (int i = threadIdx.x; i < HID * CIN3; i += 256) {
        int h = i / CIN3, c = i - h * CIN3;
        float vz, vh;
        if (c < 16) {
            vz = Wz[(0 * 48 + c) * 32 + h] + Wz[(2 * 48 + c) * 32 + h];
            vh = Wh[(0 * 48 + c) * 32 + h] + Wh[(2 * 48 + c) * 32 + h];
        } else if (c < 32) {
            vz = Wz[(1 * 48 + (c - 16)) * 32 + h];
            vh = Wh[(1 * 48 + (c - 16)) * 32 + h];
        } else {
            vz = Wz[(3 * 48 + (c - 32)) * 32 + h];
            vh = Wh[(3 * 48 + (c - 32)) * 32 + h];
        }
        sWz[i] = vz; sWh[i] = vh;
    }
    if (threadIdx.x < HID) { sBz[threadIdx.x] = bz[threadIdx.x]; sBh[threadIdx.x] = bh[threadIdx.x]; }
    for (int i = threadIdx.x; i < HID * OUTD; i += 256) sLW[i] = linW[i];
    if (threadIdx.x < OUTD) sLb[threadIdx.x] = linb[threadIdx.x];
    __syncthreads();

    int n = blockIdx.x * 256 + threadIdx.x;
    if (n >= N_NODES) return;

    float feat[CIN3];
#pragma unroll
    for (int q = 0; q < 4; ++q) {
        float4 v = ((const float4*)(x + (size_t)n * NF))[q];
        feat[q*4+0]=v.x; feat[q*4+1]=v.y; feat[q*4+2]=v.z; feat[q*4+3]=v.w;
    }
#pragma unroll
    for (int q = 0; q < 4; ++q) {
        float4 v = ((const float4*)(To + (size_t)n * NF))[q];
        feat[16+q*4+0]=v.x; feat[16+q*4+1]=v.y; feat[16+q*4+2]=v.z; feat[16+q*4+3]=v.w;
    }
#pragma unroll
    for (int q = 0; q < 4; ++q) {
        float4 v = ((const float4*)(Ti + (size_t)n * NF))[q];
        feat[32+q*4+0]=v.x; feat[32+q*4+1]=v.y; feat[32+q*4+2]=v.z; feat[32+q*4+3]=v.w;
    }

    float o[OUTD];
#pragma unroll
    for (int j = 0; j < OUTD; ++j) o[j] = sLb[j];

#pragma unroll 2
    for (int h = 0; h < HID; ++h) {
        float az = sBz[h];
        float ah = sBh[h];
        const float4* wz4 = (const float4*)(sWz + h * CIN3);
        const float4* wh4 = (const float4*)(sWh + h * CIN3);
#pragma unroll
        for (int q = 0; q < CIN3 / 4; ++q) {
            float4 wz = wz4[q];
            float4 wh = wh4[q];
            float f0 = feat[q*4+0], f1 = feat[q*4+1], f2 = feat[q*4+2], f3 = feat[q*4+3];
            az += f0*wz.x + f1*wz.y + f2*wz.z + f3*wz.w;
            ah += f0*wh.x + f1*wh.y + f2*wh.z + f3*wh.w;
        }
        float z  = 1.0f / (1.0f + expf(-az));
        float ht = tanhf(ah);
        float r  = fmaxf((1.0f - z) * ht, 0.0f);   // H = (1-Z)*H_tilde (H0=0), relu
#pragma unroll
        for (int j = 0; j < OUTD; ++j) o[j] += r * sLW[h * OUTD + j];
    }

    float4* op = (float4*)(out + (size_t)n * OUTD);
    op[0] = make_float4(o[0], o[1], o[2],  o[3]);
    op[1] = make_float4(o[4], o[5], o[6],  o[7]);
    op[2] = make_float4(o[8], o[9], o[10], o[11]);
}

// ============================================================================
// FALLBACK (ws too small): compact atomic path (round-2 structure)
// ============================================================================
__global__ void zero_kernel(float* __restrict__ p, int n) {
    int i = blockIdx.x * blockDim.x + threadIdx.x;
    int stride = gridDim.x * blockDim.x;
    for (; i < n; i += stride) p[i] = 0.0f;
}
__global__ void degree_compact(const int* __restrict__ ei, const float* __restrict__ ew,
                               float* __restrict__ deg_out, float* __restrict__ deg_in) {
    int e = blockIdx.x * blockDim.x + threadIdx.x;
    if (e >= N_EDGES) return;
    atomicAdd(&deg_out[ei[e]], ew[e]);
    atomicAdd(&deg_in[ei[N_EDGES + e]], ew[e]);
}
__global__ void rcp_compact(float* __restrict__ a, float* __restrict__ b) {
    int n = blockIdx.x * blockDim.x + threadIdx.x;
    if (n >= N_NODES) return;
    a[n] = 1.0f / a[n]; b[n] = 1.0f / b[n];
}
__global__ __launch_bounds__(256)
void scatter_kernel(const int* __restrict__ ei, const float* __restrict__ x,
                    const float* __restrict__ inv_out, const float* __restrict__ inv_in,
                    float* __restrict__ To, float* __restrict__ Ti) {
    int t = blockIdx.x * blockDim.x + threadIdx.x;
    if (t >= N_EDGES * NF) return;
    int e = t >> 4, f = t & 15;
    int src = ei[e], dst = ei[N_EDGES + e];
    atomicAdd(&To[dst * NF + f], x[src * NF + f] * inv_out[src]);
    atomicAdd(&Ti[src * NF + f], x[dst * NF + f] * inv_in[dst]);
}

// ============================================================================
extern "C" void kernel_launch(void* const* d_in, const int* in_sizes, int n_in,
                              void* d_out, int out_size, void* d_ws, size_t ws_size,
                              hipStream_t stream) {
    const float* x    = (const float*)d_in[0];
    const int*   ei   = (const int*)  d_in[1];
    const float* ew   = (const float*)d_in[2];
    const float* Wz   = (const float*)d_in[3];
    const float* bz   = (const float*)d_in[4];
    // d_in[5], d_in[6] (W_r, b_r) dead: H0 == 0 makes the reset gate unused.
    const float* Wh   = (const float*)d_in[7];
    const float* bh   = (const float*)d_in[8];
    const float* linW = (const float*)d_in[9];
    const float* linb = (const float*)d_in[10];

    float* ws = (float*)d_ws;

    // ---- main-path workspace layout (dwords) ----
    size_t off = 0;
    uint* recXD = (uint*)(ws + off);  off += (size_t)N_EDGES;
    uint* recWD = (uint*)(ws + off);  off += (size_t)N_EDGES;
    uint* recXS = (uint*)(ws + off);  off += (size_t)N_EDGES;
    uint* recWS = (uint*)(ws + off);  off += (size_t)N_EDGES;
    uint* cntD  = (uint*)(ws + off);  off += (size_t)NB * PBLK;
    uint* cntS  = (uint*)(ws + off);  off += (size_t)NB * PBLK;
    uint* offD  = (uint*)(ws + off);  off += (size_t)NB * PBLK;
    uint* offS  = (uint*)(ws + off);  off += (size_t)NB * PBLK;
    uint* totD  = (uint*)(ws + off);  off += NB;
    uint* totS  = (uint*)(ws + off);  off += NB;
    uint* baseD = (uint*)(ws + off);  off += NB + 1;
    uint* baseS = (uint*)(ws + off);  off += NB + 1;
    ushort* xs  = (ushort*)(ws + off); off += (size_t)N_NODES * NF / 2;
    ushort* xd  = (ushort*)(ws + off); off += (size_t)N_NODES * NF / 2;
    float* To   = ws + off;           off += (size_t)NF * N_NODES;
    float* Ti   = ws + off;           off += (size_t)NF * N_NODES;
    size_t need = off * sizeof(float);

    if (ws_size >= need) {
        p1_count    <<<PBLK,  PT,  0, stream>>>(ei, cntD, cntS);
        p2a_rowsum  <<<2*NB,  256, 0, stream>>>(cntD, cntS, totD, totS);
        p2b_scan    <<<1,     256, 0, stream>>>(totD, totS, baseD, baseS);
        p2c_rowscan <<<2*NB,  256, 0, stream>>>(cntD, cntS, baseD, baseS, offD, offS);
        p3_scatter  <<<PBLK,  PT,  0, stream>>>(ei, ew, cntD, cntS, offD, offS,
                                                recXD, recWD, recXS, recWS);
        kdeg2       <<<NB,    256, 0, stream>>>(recWD, recWS, baseD, baseS, x, xs, xd);
        p4_fixed    <<<2*NB,  256, 0, stream>>>(recXD, recXS, baseD, baseS, xs, xd, To, Ti);
        node_kernel <<<(N_NODES + 255) / 256, 256, 0, stream>>>(x, To, Ti, Wz, Wh, bz, bh,
                                                                linW, linb, (float*)d_out);
    } else {
        float* fTo  = ws;
        float* fTi  = ws + 16 * N_NODES;
        float* fIo  = ws + 32 * N_NODES;
        float* fIi  = ws + 33 * N_NODES;
        zero_kernel<<<2048, 256, 0, stream>>>(fTo, 34 * N_NODES);
        degree_compact<<<(N_EDGES + 255) / 256, 256, 0, stream>>>(ei, ew, fIo, fIi);
        rcp_compact<<<(N_NODES + 255) / 256, 256, 0, stream>>>(fIo, fIi);
        scatter_kernel<<<(N_EDGES * NF + 255) / 256, 256, 0, stream>>>(ei, x, fIo, fIi, fTo, fTi);
        node_kernel<<<(N_NODES + 255) / 256, 256, 0, stream>>>(x, fTo, fTi, Wz, Wh, bz, bh,
                                                               linW, linb, (float*)d_out);
    }
}